// Round 1
// baseline (645.473 us; speedup 1.0000x reference)
//
#include <hip/hip_runtime.h>
#include <math.h>

#define SS 9
#define EE 32
#define TPB 256
#define PADW 33

// d_ws float offsets (derived weights, computed by prep kernel each launch)
#define WS_M0   0      // M_h[e][e2], h-major, 2*1024
#define WS_PT0  2048   // PT_h[e][f] = P_h[f][e], 2*1024
#define WS_UB   4096   // ub_h[e],  2*32
#define WS_U    4160   // u_h[e],   2*32
#define WS_BO2  4224   // bo2[f],   32
#define WS_C    4256   // c_h,      2

// qk[h][s]*0.25-scale is folded:
//   0.25*qk = c_h + q.u_h + k_s.(ub_h + q^T M_h)
//   out[f]  = bo2[f] + sum_h vbar_h . PT_h[:,f]   (uses sum_s p = 1)
__global__ void gauss_prep_kernel(const float* __restrict__ ipw,
                                  const float* __restrict__ ipb,
                                  const float* __restrict__ opw,
                                  const float* __restrict__ opb,
                                  float* __restrict__ dw) {
  const int tid = threadIdx.x;
  // M_h[e][e2] = 0.25 * sum_d Wq[h*16+d][e] * Wk[h*16+d][e2]
  for (int idx = tid; idx < 2048; idx += TPB) {
    const int h = idx >> 10, e = (idx >> 5) & 31, e2 = idx & 31;
    float acc = 0.f;
    for (int d = 0; d < 16; ++d)
      acc += ipw[(h * 16 + d) * 32 + e] * ipw[(32 + h * 16 + d) * 32 + e2];
    dw[WS_M0 + idx] = 0.25f * acc;
  }
  // PT_h[e][f] = sum_d Wo[f][h*16+d] * Wv[h*16+d][e]
  for (int idx = tid; idx < 2048; idx += TPB) {
    const int h = idx >> 10, e = (idx >> 5) & 31, f = idx & 31;
    float acc = 0.f;
    for (int d = 0; d < 16; ++d)
      acc += opw[f * 32 + h * 16 + d] * ipw[(64 + h * 16 + d) * 32 + e];
    dw[WS_PT0 + idx] = acc;
  }
  if (tid < 64) {
    const int h = tid >> 5, e = tid & 31;
    float a_ub = 0.f, a_u = 0.f;
    for (int d = 0; d < 16; ++d) {
      a_ub += ipb[h * 16 + d] * ipw[(32 + h * 16 + d) * 32 + e];
      a_u  += ipw[(h * 16 + d) * 32 + e] * ipb[32 + h * 16 + d];
    }
    dw[WS_UB + tid] = 0.25f * a_ub;
    dw[WS_U + tid]  = 0.25f * a_u;
  } else if (tid < 96) {
    const int f = tid - 64;
    float acc = opb[f];
    for (int j = 0; j < 32; ++j) acc += ipb[64 + j] * opw[f * 32 + j];
    dw[WS_BO2 + f] = acc;
  } else if (tid < 98) {
    const int h = tid - 96;
    float acc = 0.f;
    for (int d = 0; d < 16; ++d) acc += ipb[h * 16 + d] * ipb[32 + h * 16 + d];
    dw[WS_C + h] = 0.25f * acc;
  }
}

__global__ __launch_bounds__(TPB) void gauss_attn_kernel(
    const float* __restrict__ query,
    const float* __restrict__ key,
    const float* __restrict__ value,
    const float* __restrict__ gauss,
    const float* __restrict__ dw,
    float* __restrict__ out) {
  __shared__ float tile[TPB * PADW];   // 256 rows x 32 (+1 pad), reused q/k/v/out
  __shared__ float gtile[TPB * SS];    // linear; (9t+s)%32 -> <=2-way conflicts (free)

  const int tid = threadIdx.x;
  const long b0 = (long)blockIdx.x * TPB;

  // ---- gauss tile: 2304 contiguous floats, coalesced ----
  {
    const float* g = gauss + b0 * SS;
    for (int i = tid; i < TPB * SS; i += TPB) gtile[i] = g[i];
  }
  // ---- q tile: 8192 contiguous floats, float4 coalesced -> padded rows ----
  {
    const float4* q4 = (const float4*)(query + b0 * EE);
    #pragma unroll
    for (int i = 0; i < 8; ++i) {
      const int idx = i * TPB + tid;
      const float4 v = q4[idx];
      const int r = idx >> 3, j = idx & 7;
      float* t = &tile[r * PADW + 4 * j];
      t[0] = v.x; t[1] = v.y; t[2] = v.z; t[3] = v.w;
    }
  }
  __syncthreads();

  float qreg[32];
  #pragma unroll
  for (int e = 0; e < 32; ++e) qreg[e] = tile[tid * PADW + e];

  float gw[SS];
  #pragma unroll
  for (int s = 0; s < SS; ++s) gw[s] = __expf(-10.0f * gtile[tid * SS + s]);

  // t0[h] = c_h + q . u_h
  float t00 = dw[WS_C + 0], t01 = dw[WS_C + 1];
  #pragma unroll
  for (int e = 0; e < 32; ++e) {
    t00 += qreg[e] * dw[WS_U + e];
    t01 += qreg[e] * dw[WS_U + 32 + e];
  }

  // wv_h = ub_h + q^T M_h   (weights read with uniform index -> s_load/SGPR operand)
  float wv0[32], wv1[32];
  #pragma unroll
  for (int e2 = 0; e2 < 32; ++e2) {
    wv0[e2] = dw[WS_UB + e2];
    wv1[e2] = dw[WS_UB + 32 + e2];
  }
  #pragma unroll
  for (int e = 0; e < 32; ++e) {
    const float qe = qreg[e];
    #pragma unroll
    for (int e2 = 0; e2 < 32; ++e2) {
      wv0[e2] += qe * dw[WS_M0 + e * 32 + e2];
      wv1[e2] += qe * dw[WS_M0 + 1024 + e * 32 + e2];
    }
  }

  // ---- K phase: per s, stage 256x32 tile, each thread dots its own row ----
  float qk0[SS], qk1[SS];
  #pragma unroll
  for (int s = 0; s < SS; ++s) {
    __syncthreads();
    #pragma unroll
    for (int i = 0; i < 8; ++i) {
      const int idx = i * TPB + tid;
      const int r = idx >> 3, j = idx & 7;
      const float4 v =
          *(const float4*)(key + (b0 + r) * (long)(SS * EE) + s * EE + 4 * j);
      float* t = &tile[r * PADW + 4 * j];
      t[0] = v.x; t[1] = v.y; t[2] = v.z; t[3] = v.w;
    }
    __syncthreads();
    float a0 = t00, a1 = t01;
    #pragma unroll
    for (int e = 0; e < 32; ++e) {
      const float kv = tile[tid * PADW + e];  // bank (t+e)%32: conflict-free
      a0 += wv0[e] * kv;
      a1 += wv1[e] * kv;
    }
    qk0[s] = a0; qk1[s] = a1;
  }

  // ---- gauss-weighted softmax over s, per head ----
  float p0[SS], p1[SS];
  {
    float m0 = -1e30f, m1 = -1e30f;
    #pragma unroll
    for (int s = 0; s < SS; ++s) {
      qk0[s] *= gw[s]; qk1[s] *= gw[s];
      m0 = fmaxf(m0, qk0[s]); m1 = fmaxf(m1, qk1[s]);
    }
    float l0 = 0.f, l1 = 0.f;
    #pragma unroll
    for (int s = 0; s < SS; ++s) {
      p0[s] = __expf(qk0[s] - m0); l0 += p0[s];
      p1[s] = __expf(qk1[s] - m1); l1 += p1[s];
    }
    const float r0 = 1.f / l0, r1 = 1.f / l1;
    #pragma unroll
    for (int s = 0; s < SS; ++s) { p0[s] *= r0; p1[s] *= r1; }
  }

  // ---- V phase: vbar_h[e] = sum_s p[h][s] * v_s[e] ----
  float vb0[32], vb1[32];
  #pragma unroll
  for (int e = 0; e < 32; ++e) { vb0[e] = 0.f; vb1[e] = 0.f; }
  #pragma unroll
  for (int s = 0; s < SS; ++s) {
    __syncthreads();
    #pragma unroll
    for (int i = 0; i < 8; ++i) {
      const int idx = i * TPB + tid;
      const int r = idx >> 3, j = idx & 7;
      const float4 v =
          *(const float4*)(value + (b0 + r) * (long)(SS * EE) + s * EE + 4 * j);
      float* t = &tile[r * PADW + 4 * j];
      t[0] = v.x; t[1] = v.y; t[2] = v.z; t[3] = v.w;
    }
    __syncthreads();
    const float w0 = p0[s], w1 = p1[s];
    #pragma unroll
    for (int e = 0; e < 32; ++e) {
      const float vv = tile[tid * PADW + e];
      vb0[e] += w0 * vv;
      vb1[e] += w1 * vv;
    }
  }

  // ---- fused out-proj: out[f] = bo2[f] + sum_e vb0[e]*PT0[e][f] + vb1[e]*PT1[e][f]
  float o[32];
  #pragma unroll
  for (int f = 0; f < 32; ++f) o[f] = dw[WS_BO2 + f];
  #pragma unroll
  for (int e = 0; e < 32; ++e) {
    const float x0 = vb0[e], x1 = vb1[e];
    #pragma unroll
    for (int f = 0; f < 32; ++f) {
      o[f] += x0 * dw[WS_PT0 + e * 32 + f];
      o[f] += x1 * dw[WS_PT0 + 1024 + e * 32 + f];
    }
  }

  // ---- coalesced store via LDS ----
  __syncthreads();
  #pragma unroll
  for (int f = 0; f < 32; ++f) tile[tid * PADW + f] = o[f];
  __syncthreads();
  {
    float4* o4 = (float4*)(out + b0 * EE);
    #pragma unroll
    for (int i = 0; i < 8; ++i) {
      const int idx = i * TPB + tid;
      const int r = idx >> 3, j = idx & 7;
      const float* t = &tile[r * PADW + 4 * j];
      o4[idx] = make_float4(t[0], t[1], t[2], t[3]);
    }
  }
}

extern "C" void kernel_launch(void* const* d_in, const int* in_sizes, int n_in,
                              void* d_out, int out_size, void* d_ws, size_t ws_size,
                              hipStream_t stream) {
  const float* query = (const float*)d_in[0];
  const float* key   = (const float*)d_in[1];
  const float* value = (const float*)d_in[2];
  const float* gauss = (const float*)d_in[3];
  const float* ipw   = (const float*)d_in[4];
  const float* ipb   = (const float*)d_in[5];
  const float* opw   = (const float*)d_in[6];
  const float* opb   = (const float*)d_in[7];
  float* out = (float*)d_out;
  float* dw  = (float*)d_ws;   // needs 4258 floats (~17 KB)

  const int n = in_sizes[0] / EE;  // 262144 batches
  gauss_prep_kernel<<<1, TPB, 0, stream>>>(ipw, ipb, opw, opb, dw);
  gauss_attn_kernel<<<n / TPB, TPB, 0, stream>>>(query, key, value, gauss, dw, out);
}